// Round 2
// baseline (1235.747 us; speedup 1.0000x reference)
//
#include <hip/hip_runtime.h>
#include <hip/hip_fp16.h>
#include <type_traits>

#define NN 10000
#define EE 160000

// ---------------------------------------------------------------------------
// K1: Xp = clin(X, Wp) + bp ; Xn = Xp / (tnorm(Xp)+1) ; decompose -> D1[n][10][128]
// D1 comps: 0:lam 1:a01 2:a02 3:a12 4:s00 5:s01 6:s02 7:s11 8:s12 9:s22
// LDS: 128*129 half (33KB) + 9*132 f32 (4.75KB) + 128*9 f32 (4.6KB) = 42.4KB
// ---------------------------------------------------------------------------
__global__ __launch_bounds__(256) void k_node_prep(
    const float* __restrict__ X, const float* __restrict__ Wp,
    const float* __restrict__ bp,
    __half* __restrict__ Xn, __half* __restrict__ D1)
{
  __shared__ __half WlT[128*129];  // [c][o] transposed
  __shared__ float Xl[9*132];      // [ij][c]
  __shared__ float Xpl[128*9];     // [o][ij]
  const int t = threadIdx.x;
  for (int idx = t; idx < 128*128; idx += 256) {
    int o = idx >> 7, c = idx & 127;
    WlT[c*129 + o] = __float2half(Wp[idx]);
  }
  const int o = t & 127, ij0 = t >> 7;   // ij0 in {0,1}
  const float bv = bp[o];
  for (int n = blockIdx.x; n < NN; n += gridDim.x) {
    __syncthreads();
    for (int idx = t; idx < 1152; idx += 256) {
      int c = idx / 9, ij = idx - c*9;
      Xl[ij*132 + c] = X[(size_t)n*1152 + idx];
    }
    __syncthreads();
    float a0=0.f, a1=0.f, a2=0.f, a3=0.f, a4=0.f;
    #pragma unroll 4
    for (int c = 0; c < 128; ++c) {
      float wv = (float)WlT[c*129 + o];
      a0 += wv * Xl[(ij0+0)*132 + c];
      a1 += wv * Xl[(ij0+2)*132 + c];
      a2 += wv * Xl[(ij0+4)*132 + c];
      a3 += wv * Xl[(ij0+6)*132 + c];
      a4 += wv * Xl[8*132 + c];          // used only when ij0==0
    }
    Xpl[o*9 + ij0+0] = a0 + bv;
    Xpl[o*9 + ij0+2] = a1 + bv;
    Xpl[o*9 + ij0+4] = a2 + bv;
    Xpl[o*9 + ij0+6] = a3 + bv;
    if (ij0 == 0) Xpl[o*9 + 8] = a4 + bv;
    __syncthreads();
    if (t < 128) {
      float m[9], ss = 0.f;
      #pragma unroll
      for (int ij = 0; ij < 9; ++ij) { m[ij] = Xpl[t*9+ij]; ss += m[ij]*m[ij]; }
      ss = fmaxf(ss, 0.01f);
      float inv = 1.f / (ss + 1.f);
      #pragma unroll
      for (int ij = 0; ij < 9; ++ij) m[ij] *= inv;
      __half* xo = &Xn[(size_t)n*1152 + t*9];
      #pragma unroll
      for (int ij = 0; ij < 9; ++ij) xo[ij] = __float2half(m[ij]);
      float lam = (m[0]+m[4]+m[8]) * (1.f/3.f);
      __half* Dn = &D1[(size_t)n*1280];
      Dn[0*128+t] = __float2half(lam);
      Dn[1*128+t] = __float2half(0.5f*(m[1]-m[3]));
      Dn[2*128+t] = __float2half(0.5f*(m[2]-m[6]));
      Dn[3*128+t] = __float2half(0.5f*(m[5]-m[7]));
      Dn[4*128+t] = __float2half(m[0]-lam);
      Dn[5*128+t] = __float2half(0.5f*(m[1]+m[3]));
      Dn[6*128+t] = __float2half(0.5f*(m[2]+m[6]));
      Dn[7*128+t] = __float2half(m[4]-lam);
      Dn[8*128+t] = __float2half(0.5f*(m[5]+m[8-3]));
      Dn[9*128+t] = __float2half(m[8]-lam);
    }
  }
}

// ---------------------------------------------------------------------------
// Generic tiled GEMM: C[m][n] = cut? (act(sum_k A[m][k]*W[n][k]+b[n]))*C(ew[m])
// BM=BN=64, BK=32, 256 threads, 4x4 micro-tile.
// PSEL: blockIdx.z = p (0..9): W = p==0?W0 : p<4?W1 : W2; A,C offset by p*128
// ---------------------------------------------------------------------------
template<typename TA, typename TC, bool ACT, bool CUT, bool PSEL>
__global__ __launch_bounds__(256) void k_gemm(
    const TA* __restrict__ A, int lda,
    const float* __restrict__ W0, const float* __restrict__ W1, const float* __restrict__ W2,
    const float* __restrict__ bias, const float* __restrict__ cw,
    TC* __restrict__ C, int ldc,
    int M, int K)
{
  __shared__ float As[32][68];
  __shared__ float Bs[32][68];
  const int t = threadIdx.x;
  const int m0g = blockIdx.x * 64;
  const int n0g = blockIdx.y * 64;
  const float* W = W0;
  const TA* Ab = A;
  TC* Cb = C;
  if (PSEL) {
    int p = blockIdx.z;
    W  = (p == 0) ? W0 : (p < 4 ? W1 : W2);
    Ab = A + p*128;
    Cb = C + p*128;
  }
  const int tn = (t & 15) * 4;
  const int tm = (t >> 4) * 4;
  float acc[4][4] = {};
  for (int k0 = 0; k0 < K; k0 += 32) {
    #pragma unroll
    for (int l = 0; l < 8; ++l) {
      int idx = t + l*256;
      int mm = idx >> 5, kk = idx & 31;
      int gm = m0g + mm;
      As[kk][mm] = (gm < M) ? (float)Ab[(size_t)gm*lda + (k0 + kk)] : 0.f;
      Bs[kk][mm] = W[(size_t)(n0g + mm)*K + (k0 + kk)];
    }
    __syncthreads();
    #pragma unroll
    for (int k = 0; k < 32; ++k) {
      float av[4], bv[4];
      #pragma unroll
      for (int i = 0; i < 4; ++i) av[i] = As[k][tm+i];
      #pragma unroll
      for (int j = 0; j < 4; ++j) bv[j] = Bs[k][tn+j];
      #pragma unroll
      for (int i = 0; i < 4; ++i)
        #pragma unroll
        for (int j = 0; j < 4; ++j)
          acc[i][j] += av[i]*bv[j];
    }
    __syncthreads();
  }
  #pragma unroll
  for (int i = 0; i < 4; ++i) {
    int gm = m0g + tm + i;
    if (gm >= M) continue;
    float Cf = 1.f;
    if (CUT) {
      float wv = cw[gm];
      Cf = (wv < 5.f) ? 0.5f*(__cosf(wv*0.62831853071795864769f) + 1.f) : 0.f;
    }
    #pragma unroll
    for (int j = 0; j < 4; ++j) {
      int gn = n0g + tn + j;
      float v = acc[i][j];
      if (bias) v += bias[gn];
      if (ACT)  v = v / (1.f + __expf(-v));   // silu
      if (CUT)  v *= Cf;
      if constexpr (std::is_same<TC, __half>::value)
        Cb[(size_t)gm*ldc + gn] = __float2half(v);
      else
        Cb[(size_t)gm*ldc + gn] = v;
    }
  }
}

// ---------------------------------------------------------------------------
// CSR build over src
// ---------------------------------------------------------------------------
__global__ void k_zero_i(int* __restrict__ p, int n) {
  int i = blockIdx.x*256 + threadIdx.x;
  if (i < n) p[i] = 0;
}
__global__ void k_hist(const int* __restrict__ src, int* __restrict__ cnt) {
  int e = blockIdx.x*256 + threadIdx.x;
  if (e < EE) atomicAdd(&cnt[src[e]], 1);
}
__global__ __launch_bounds__(1024) void k_scan(const int* __restrict__ cnt,
                                               int* __restrict__ off,
                                               int* __restrict__ cur) {
  __shared__ int s[1024];
  __shared__ int carry;
  int t = threadIdx.x;
  if (t == 0) carry = 0;
  __syncthreads();
  for (int base = 0; base < NN; base += 1024) {
    int i = base + t;
    int v = (i < NN) ? cnt[i] : 0;
    s[t] = v; __syncthreads();
    for (int d = 1; d < 1024; d <<= 1) {
      int x = (t >= d) ? s[t-d] : 0; __syncthreads();
      s[t] += x; __syncthreads();
    }
    int incl = s[t];
    int total = s[1023];
    int excl = incl - v + carry;
    if (i < NN) { off[i] = excl; cur[i] = excl; }
    __syncthreads();
    if (t == 0) carry += total;
    __syncthreads();
  }
  if (t == 0) off[NN] = carry;
}
__global__ void k_scatter(const int* __restrict__ src, int* __restrict__ cur,
                          int* __restrict__ elist) {
  int e = blockIdx.x*256 + threadIdx.x;
  if (e < EE) { int pos = atomicAdd(&cur[src[e]], 1); elist[pos] = e; }
}

// ---------------------------------------------------------------------------
// Message passing: one block per node; decomposed accumulation (I:1,A:3,S:6).
// ea already includes the cutoff factor.
// ---------------------------------------------------------------------------
__global__ __launch_bounds__(256) void k_message(
    const __half* __restrict__ ea, const __half* __restrict__ T1,
    const int* __restrict__ dstArr,
    const int* __restrict__ off, const int* __restrict__ elist,
    __half* __restrict__ msg)
{
  int n = blockIdx.x;
  int t = threadIdx.x;
  int o = t & 127, ph = t >> 7;
  int e0 = off[n], e1 = off[n+1];
  float acc0=0.f, acc1=0.f, acc2=0.f, acc3=0.f, acc4=0.f;
  for (int ii = e0; ii < e1; ++ii) {
    int e = elist[ii];
    int d = dstArr[e];
    const __half* he = &ea[(size_t)e*384 + 3*o];
    const __half* Td = &T1[(size_t)d*1280 + o];
    if (ph == 0) {
      float f0 = (float)he[0];
      float f1 = (float)he[1];
      float f2 = (float)he[2];
      acc0 += f0 * (float)Td[0];      // lam'
      acc1 += f1 * (float)Td[128];    // a0'
      acc2 += f1 * (float)Td[256];    // a1'
      acc3 += f1 * (float)Td[384];    // a2'
      acc4 += f2 * (float)Td[512];    // s00'
    } else {
      float f2 = (float)he[2];
      acc0 += f2 * (float)Td[640];    // s01'
      acc1 += f2 * (float)Td[768];    // s02'
      acc2 += f2 * (float)Td[896];    // s11'
      acc3 += f2 * (float)Td[1024];   // s12'
      acc4 += f2 * (float)Td[1152];   // s22'
    }
  }
  __half* mn = &msg[(size_t)n*1280 + o];
  int pb = ph * 5;
  mn[(pb+0)*128] = __float2half(acc0);
  mn[(pb+1)*128] = __float2half(acc1);
  mn[(pb+2)*128] = __float2half(acc2);
  mn[(pb+3)*128] = __float2half(acc3);
  mn[(pb+4)*128] = __float2half(acc4);
}

// ---------------------------------------------------------------------------
// Bracket: B = M*Y + Y*M ; decompose ; /(tnorm(B)+1) -> D2
// NOTE: D2 may alias T1 (in-place). No __restrict__ on those params; every
// output depends on `inv` (all loads), so stores cannot precede loads.
// ---------------------------------------------------------------------------
__global__ __launch_bounds__(256) void k_bracket(
    const __half* __restrict__ msgp, const __half* T1, __half* D2)
{
  int idx = blockIdx.x*256 + threadIdx.x;
  int n = idx >> 7, o = idx & 127;
  const __half* Mc = &msgp[(size_t)n*1280 + o];
  const __half* Yc = &T1[(size_t)n*1280 + o];
  float Mm[9], Ym[9];
  {
    float lam=(float)Mc[0], a0=(float)Mc[128], a1=(float)Mc[256], a2=(float)Mc[384];
    float s00=(float)Mc[512], s01=(float)Mc[640], s02=(float)Mc[768];
    float s11=(float)Mc[896], s12=(float)Mc[1024], s22=(float)Mc[1152];
    Mm[0]=lam+s00; Mm[1]=a0+s01;  Mm[2]=a1+s02;
    Mm[3]=s01-a0;  Mm[4]=lam+s11; Mm[5]=a2+s12;
    Mm[6]=s02-a1;  Mm[7]=s12-a2;  Mm[8]=lam+s22;
  }
  {
    float lam=(float)Yc[0], a0=(float)Yc[128], a1=(float)Yc[256], a2=(float)Yc[384];
    float s00=(float)Yc[512], s01=(float)Yc[640], s02=(float)Yc[768];
    float s11=(float)Yc[896], s12=(float)Yc[1024], s22=(float)Yc[1152];
    Ym[0]=lam+s00; Ym[1]=a0+s01;  Ym[2]=a1+s02;
    Ym[3]=s01-a0;  Ym[4]=lam+s11; Ym[5]=a2+s12;
    Ym[6]=s02-a1;  Ym[7]=s12-a2;  Ym[8]=lam+s22;
  }
  float B[9];
  #pragma unroll
  for (int i = 0; i < 3; ++i) {
    #pragma unroll
    for (int j = 0; j < 3; ++j) {
      float s = 0.f;
      #pragma unroll
      for (int k = 0; k < 3; ++k)
        s += Mm[i*3+k]*Ym[k*3+j] + Ym[i*3+k]*Mm[k*3+j];
      B[i*3+j] = s;
    }
  }
  float lamb = (B[0]+B[4]+B[8]) * (1.f/3.f);
  float ss = 0.f;
  #pragma unroll
  for (int q = 0; q < 9; ++q) ss += B[q]*B[q];
  float inv = 1.f / (fmaxf(ss, 0.01f) + 1.f);
  __half* Dn = &D2[(size_t)n*1280 + o];
  Dn[0]    = __float2half(lamb*inv);
  Dn[128]  = __float2half(0.5f*(B[1]-B[3])*inv);
  Dn[256]  = __float2half(0.5f*(B[2]-B[6])*inv);
  Dn[384]  = __float2half(0.5f*(B[5]-B[7])*inv);
  Dn[512]  = __float2half((B[0]-lamb)*inv);
  Dn[640]  = __float2half(0.5f*(B[1]+B[3])*inv);
  Dn[768]  = __float2half(0.5f*(B[2]+B[6])*inv);
  Dn[896]  = __float2half((B[4]-lamb)*inv);
  Dn[1024] = __float2half(0.5f*(B[5]+B[7])*inv);
  Dn[1152] = __float2half((B[8]-lamb)*inv);
}

// ---------------------------------------------------------------------------
// Final: out = Xn + reconstruct(Tb)
// ---------------------------------------------------------------------------
__global__ __launch_bounds__(256) void k_final(
    const __half* __restrict__ Xn, const __half* __restrict__ Tb,
    float* __restrict__ out)
{
  int idx = blockIdx.x*256 + threadIdx.x;
  int n = idx >> 7, o = idx & 127;
  const __half* Tc = &Tb[(size_t)n*1280 + o];
  float lam=(float)Tc[0], a0=(float)Tc[128], a1=(float)Tc[256], a2=(float)Tc[384];
  float s00=(float)Tc[512], s01=(float)Tc[640], s02=(float)Tc[768];
  float s11=(float)Tc[896], s12=(float)Tc[1024], s22=(float)Tc[1152];
  const __half* xc = &Xn[(size_t)n*1152 + o*9];
  float* oc = &out[(size_t)n*1152 + o*9];
  oc[0] = (float)xc[0] + lam + s00;
  oc[1] = (float)xc[1] + a0  + s01;
  oc[2] = (float)xc[2] + a1  + s02;
  oc[3] = (float)xc[3] - a0  + s01;
  oc[4] = (float)xc[4] + lam + s11;
  oc[5] = (float)xc[5] + a2  + s12;
  oc[6] = (float)xc[6] - a1  + s02;
  oc[7] = (float)xc[7] - a2  + s12;
  oc[8] = (float)xc[8] + lam + s22;
}

// ---------------------------------------------------------------------------
extern "C" void kernel_launch(void* const* d_in, const int* in_sizes, int n_in,
                              void* d_out, int out_size, void* d_ws, size_t ws_size,
                              hipStream_t stream)
{
  const float* X     = (const float*)d_in[0];
  const float* ew    = (const float*)d_in[1];
  const float* eattr = (const float*)d_in[2];
  const float* Wp    = (const float*)d_in[3];
  const float* bp    = (const float*)d_in[4];
  const float* Ws0   = (const float*)d_in[5];
  const float* bs0   = (const float*)d_in[6];
  const float* Ws1   = (const float*)d_in[7];
  const float* bs1   = (const float*)d_in[8];
  const float* Ws2   = (const float*)d_in[9];
  const float* bs2   = (const float*)d_in[10];
  const int*   eidx  = (const int*)d_in[11];
  const float* Wt0   = (const float*)d_in[12];
  const float* Wt1   = (const float*)d_in[13];
  const float* Wt2   = (const float*)d_in[14];
  const float* Wt3   = (const float*)d_in[15];
  const float* Wt4   = (const float*)d_in[16];
  const float* Wt5   = (const float*)d_in[17];
  float* out = (float*)d_out;

  // Packed lifetime-aliased layout, peak 254,161,920 B:
  //  A [0,          23,040,000)  Xn fp16                  [K1 -> final]
  //  B [23,040,000, 48,640,000)  T1 fp16 -> D2 (in-place) [K2 -> K4]
  //  C [48,640,000, 130,560,000) D1 -> h1 -> msg -> Tb    (81.92 MB)
  //  D [130,560,000,253,440,000) h0 -> ea                 (122.88 MB)
  //  csr [253,440,000, 254,161,920)
  const size_t NEED = 254161920;
  if (ws_size < NEED) return;   // diagnostic: poison-fail instead of fault

  char* base = (char*)d_ws;
  __half* Xn  = (__half*)(base);
  __half* T1  = (__half*)(base + 23040000);
  __half* D1  = (__half*)(base + 48640000);
  __half* h1  = (__half*)(base + 48640000);
  __half* msg = (__half*)(base + 48640000);
  __half* Tb  = (__half*)(base + 48640000);
  __half* h0  = (__half*)(base + 130560000);
  __half* ea  = (__half*)(base + 130560000);
  char*   csr = base + 253440000;
  int* off_  = (int*)csr;
  int* cur_  = (int*)(csr + 40960);
  int* elist = (int*)(csr + 81920);

  (void)in_sizes; (void)n_in; (void)out_size;

  // node prep + decompose
  k_node_prep<<<2500, 256, 0, stream>>>(X, Wp, bp, Xn, D1);
  // T' = clin(I,Wt0)/clin(A,Wt1)/clin(S,Wt2) as 10 GEMM slices
  k_gemm<__half, __half, false, false, true><<<dim3(157, 2, 10), 256, 0, stream>>>(
      D1, 1280, Wt0, Wt1, Wt2, nullptr, nullptr, T1, 1280, NN, 128);
  // edge MLP (cutoff folded into last layer's epilogue)
  k_gemm<float,  __half, true, false, false><<<dim3(2500, 2, 1), 256, 0, stream>>>(
      eattr, 32, Ws0, nullptr, nullptr, bs0, nullptr, h0, 128, EE, 32);
  k_gemm<__half, __half, true, false, false><<<dim3(2500, 4, 1), 256, 0, stream>>>(
      h0, 128, Ws1, nullptr, nullptr, bs1, nullptr, h1, 256, EE, 128);
  k_gemm<__half, __half, true, true,  false><<<dim3(2500, 6, 1), 256, 0, stream>>>(
      h1, 256, Ws2, nullptr, nullptr, bs2, ew, ea, 384, EE, 256);
  // CSR over src
  k_zero_i<<<40, 256, 0, stream>>>(cur_, NN);
  k_hist<<<625, 256, 0, stream>>>(eidx, cur_);
  k_scan<<<1, 1024, 0, stream>>>(cur_, off_, cur_);
  k_scatter<<<625, 256, 0, stream>>>(eidx, cur_, elist);
  // message passing (gather T'[dst], reduce per src node)
  k_message<<<NN, 256, 0, stream>>>(ea, T1, eidx + EE, off_, elist, msg);
  // bracket + decompose + norm (D2 overwrites T1 in-place)
  k_bracket<<<5000, 256, 0, stream>>>(msg, T1, T1);
  // dX components = clin with Wt3/4/5
  k_gemm<__half, __half, false, false, true><<<dim3(157, 2, 10), 256, 0, stream>>>(
      T1, 1280, Wt3, Wt4, Wt5, nullptr, nullptr, Tb, 1280, NN, 128);
  // out = Xn + reconstruct(dX)
  k_final<<<5000, 256, 0, stream>>>(Xn, Tb, out);
}

// Round 3
// 522.876 us; speedup vs baseline: 2.3634x; 2.3634x over previous
//
#include <hip/hip_runtime.h>
#include <hip/hip_fp16.h>
#include <type_traits>

#define NN 10000
#define EE 160000

typedef _Float16 half8 __attribute__((ext_vector_type(8)));
typedef float    f32x4 __attribute__((ext_vector_type(4)));

// ---------------------------------------------------------------------------
// K1: Xp = clin(X, Wp) + bp ; Xn = Xp / (tnorm(Xp)+1) ; decompose -> D1[n][10][128]
// D1 comps: 0:lam 1:a01 2:a02 3:a12 4:s00 5:s01 6:s02 7:s11 8:s12 9:s22
// ---------------------------------------------------------------------------
__global__ __launch_bounds__(256) void k_node_prep(
    const float* __restrict__ X, const float* __restrict__ Wp,
    const float* __restrict__ bp,
    __half* __restrict__ Xn, __half* __restrict__ D1)
{
  __shared__ __half WlT[128*129];  // [c][o] transposed
  __shared__ float Xl[9*132];      // [ij][c]
  __shared__ float Xpl[128*9];     // [o][ij]
  const int t = threadIdx.x;
  for (int idx = t; idx < 128*128; idx += 256) {
    int o = idx >> 7, c = idx & 127;
    WlT[c*129 + o] = __float2half(Wp[idx]);
  }
  const int o = t & 127, ij0 = t >> 7;   // ij0 in {0,1}
  const float bv = bp[o];
  for (int n = blockIdx.x; n < NN; n += gridDim.x) {
    __syncthreads();
    for (int idx = t; idx < 1152; idx += 256) {
      int c = idx / 9, ij = idx - c*9;
      Xl[ij*132 + c] = X[(size_t)n*1152 + idx];
    }
    __syncthreads();
    float a0=0.f, a1=0.f, a2=0.f, a3=0.f, a4=0.f;
    #pragma unroll 4
    for (int c = 0; c < 128; ++c) {
      float wv = (float)WlT[c*129 + o];
      a0 += wv * Xl[(ij0+0)*132 + c];
      a1 += wv * Xl[(ij0+2)*132 + c];
      a2 += wv * Xl[(ij0+4)*132 + c];
      a3 += wv * Xl[(ij0+6)*132 + c];
      a4 += wv * Xl[8*132 + c];          // used only when ij0==0
    }
    Xpl[o*9 + ij0+0] = a0 + bv;
    Xpl[o*9 + ij0+2] = a1 + bv;
    Xpl[o*9 + ij0+4] = a2 + bv;
    Xpl[o*9 + ij0+6] = a3 + bv;
    if (ij0 == 0) Xpl[o*9 + 8] = a4 + bv;
    __syncthreads();
    if (t < 128) {
      float m[9], ss = 0.f;
      #pragma unroll
      for (int ij = 0; ij < 9; ++ij) { m[ij] = Xpl[t*9+ij]; ss += m[ij]*m[ij]; }
      ss = fmaxf(ss, 0.01f);
      float inv = 1.f / (ss + 1.f);
      #pragma unroll
      for (int ij = 0; ij < 9; ++ij) m[ij] *= inv;
      __half* xo = &Xn[(size_t)n*1152 + t*9];
      #pragma unroll
      for (int ij = 0; ij < 9; ++ij) xo[ij] = __float2half(m[ij]);
      float lam = (m[0]+m[4]+m[8]) * (1.f/3.f);
      __half* Dn = &D1[(size_t)n*1280];
      Dn[0*128+t] = __float2half(lam);
      Dn[1*128+t] = __float2half(0.5f*(m[1]-m[3]));
      Dn[2*128+t] = __float2half(0.5f*(m[2]-m[6]));
      Dn[3*128+t] = __float2half(0.5f*(m[5]-m[7]));
      Dn[4*128+t] = __float2half(m[0]-lam);
      Dn[5*128+t] = __float2half(0.5f*(m[1]+m[3]));
      Dn[6*128+t] = __float2half(0.5f*(m[2]+m[6]));
      Dn[7*128+t] = __float2half(m[4]-lam);
      Dn[8*128+t] = __float2half(0.5f*(m[5]+m[7]));   // s12 (bug fixed: was m[5]+m[5])
      Dn[9*128+t] = __float2half(m[8]-lam);
    }
  }
}

// ---------------------------------------------------------------------------
// MFMA GEMM: C[m][n] = post( sum_k A[m][k] * W[n][k] + bias[n] )
//   - mfma_f32_16x16x32_f16, fp32 accumulate
//   - 256 thr = 4 waves; BM=128 (wave w owns rows w*32..w*32+31), BN=64
//   - wave fragment-repeat acc[2][4] (2 row-frags x 4 col-frags of 16)
//   - A frags straight from global (16B/lane, aligned); W staged fp32->fp16
//     into LDS once per block, pitch KT+8 halves (conflict-free b128 reads)
//   - XCD-bijective swizzle (m204), n-tile fastest => A m-panel L2-resident
//   - PSEL: blockIdx.z = p in 0..9: W = p==0?W0 : p<4?W1 : W2; A,C col-offset p*128
// ---------------------------------------------------------------------------
template<typename TA, int KT, bool ACT, bool CUT, bool PSEL>
__global__ __launch_bounds__(256) void k_gemm_mfma(
    const TA* __restrict__ A, int lda,
    const float* __restrict__ W0, const float* __restrict__ W1, const float* __restrict__ W2,
    const float* __restrict__ bias, const float* __restrict__ cw,
    _Float16* __restrict__ C, int ldc,
    int M, int nTiles)
{
  constexpr int PITCH = KT + 8;
  __shared__ _Float16 Bs[64 * PITCH];
  const int t = threadIdx.x;

  // XCD-bijective block swizzle (m204): each XCD gets a contiguous chunk.
  int nwg = gridDim.x;
  int bid = blockIdx.x;
  int q = nwg >> 3, rr = nwg & 7;
  int xcd = bid & 7, ii = bid >> 3;
  int swz = (xcd < rr) ? xcd*(q+1) + ii : rr*(q+1) + (xcd-rr)*q + ii;
  int nt = swz % nTiles;
  int mt = swz / nTiles;

  const float* W = W0;
  int coff = 0;
  if (PSEL) {
    int p = blockIdx.z;
    W = (p == 0) ? W0 : (p < 4 ? W1 : W2);
    coff = p * 128;
  }
  const int n0 = nt * 64;
  const int m0 = mt * 128;

  // stage B strip [64][KT] fp32 -> fp16 LDS
  #pragma unroll 4
  for (int idx = t; idx < 64*KT; idx += 256) {
    int nn = idx / KT, kk = idx & (KT-1);
    Bs[nn*PITCH + kk] = (_Float16)W[(size_t)(n0 + nn)*KT + kk];
  }
  __syncthreads();

  const int wave = t >> 6, lane = t & 63;
  const int lr = lane & 15, lq = lane >> 4;
  const int rowBase = m0 + wave*32;
  const int kBase = lq*8;

  f32x4 acc[2][4] = {};
  #pragma unroll
  for (int k0 = 0; k0 < KT; k0 += 32) {
    half8 a[2];
    #pragma unroll
    for (int r = 0; r < 2; ++r) {
      int gm = rowBase + r*16 + lr;
      if (gm > M-1) gm = M-1;
      const TA* ap = A + (size_t)gm*lda + coff + k0 + kBase;
      if constexpr (std::is_same<TA, float>::value) {
        f32x4 u0 = *reinterpret_cast<const f32x4*>(ap);
        f32x4 u1 = *reinterpret_cast<const f32x4*>(ap + 4);
        half8 av;
        #pragma unroll
        for (int j = 0; j < 4; ++j) { av[j] = (_Float16)u0[j]; av[4+j] = (_Float16)u1[j]; }
        a[r] = av;
      } else {
        a[r] = *reinterpret_cast<const half8*>(ap);
      }
    }
    half8 b[4];
    #pragma unroll
    for (int c = 0; c < 4; ++c)
      b[c] = *reinterpret_cast<const half8*>(&Bs[(c*16 + lr)*PITCH + k0 + kBase]);
    #pragma unroll
    for (int r = 0; r < 2; ++r)
      #pragma unroll
      for (int c = 0; c < 4; ++c)
        acc[r][c] = __builtin_amdgcn_mfma_f32_16x16x32_f16(a[r], b[c], acc[r][c], 0, 0, 0);
  }

  // epilogue
  float bvv[4];
  #pragma unroll
  for (int c = 0; c < 4; ++c)
    bvv[c] = bias ? bias[n0 + c*16 + lr] : 0.f;
  #pragma unroll
  for (int r = 0; r < 2; ++r) {
    #pragma unroll
    for (int j = 0; j < 4; ++j) {
      int gm = rowBase + r*16 + lq*4 + j;   // C/D: col=lane&15, row=(lane>>4)*4+reg
      if (gm >= M) continue;
      float Cf = 1.f;
      if (CUT) {
        float wv = cw[gm];
        Cf = (wv < 5.f) ? 0.5f*(__cosf(wv*0.62831853071795864769f) + 1.f) : 0.f;
      }
      _Float16* crow = C + (size_t)gm*ldc + coff + n0;
      #pragma unroll
      for (int c = 0; c < 4; ++c) {
        float v = acc[r][c][j] + bvv[c];
        if (ACT) v = v / (1.f + __expf(-v));   // silu
        if (CUT) v *= Cf;
        crow[c*16 + lr] = (_Float16)v;
      }
    }
  }
}

// ---------------------------------------------------------------------------
// CSR build over src
// ---------------------------------------------------------------------------
__global__ void k_zero_i(int* __restrict__ p, int n) {
  int i = blockIdx.x*256 + threadIdx.x;
  if (i < n) p[i] = 0;
}
__global__ void k_hist(const int* __restrict__ src, int* __restrict__ cnt) {
  int e = blockIdx.x*256 + threadIdx.x;
  if (e < EE) atomicAdd(&cnt[src[e]], 1);
}
__global__ __launch_bounds__(1024) void k_scan(const int* __restrict__ cnt,
                                               int* __restrict__ off,
                                               int* __restrict__ cur) {
  __shared__ int s[1024];
  __shared__ int carry;
  int t = threadIdx.x;
  if (t == 0) carry = 0;
  __syncthreads();
  for (int base = 0; base < NN; base += 1024) {
    int i = base + t;
    int v = (i < NN) ? cnt[i] : 0;
    s[t] = v; __syncthreads();
    for (int d = 1; d < 1024; d <<= 1) {
      int x = (t >= d) ? s[t-d] : 0; __syncthreads();
      s[t] += x; __syncthreads();
    }
    int incl = s[t];
    int total = s[1023];
    int excl = incl - v + carry;
    if (i < NN) { off[i] = excl; cur[i] = excl; }
    __syncthreads();
    if (t == 0) carry += total;
    __syncthreads();
  }
  if (t == 0) off[NN] = carry;
}
__global__ void k_scatter(const int* __restrict__ src, int* __restrict__ cur,
                          int* __restrict__ elist) {
  int e = blockIdx.x*256 + threadIdx.x;
  if (e < EE) { int pos = atomicAdd(&cur[src[e]], 1); elist[pos] = e; }
}

// ---------------------------------------------------------------------------
// Message passing: one block per node; decomposed accumulation (I:1,A:3,S:6).
// ea already includes the cutoff factor.
// ---------------------------------------------------------------------------
__global__ __launch_bounds__(256) void k_message(
    const __half* __restrict__ ea, const __half* __restrict__ T1,
    const int* __restrict__ dstArr,
    const int* __restrict__ off, const int* __restrict__ elist,
    __half* __restrict__ msg)
{
  int n = blockIdx.x;
  int t = threadIdx.x;
  int o = t & 127, ph = t >> 7;
  int e0 = off[n], e1 = off[n+1];
  float acc0=0.f, acc1=0.f, acc2=0.f, acc3=0.f, acc4=0.f;
  for (int ii = e0; ii < e1; ++ii) {
    int e = elist[ii];
    int d = dstArr[e];
    const __half* he = &ea[(size_t)e*384 + 3*o];
    const __half* Td = &T1[(size_t)d*1280 + o];
    if (ph == 0) {
      float f0 = (float)he[0];
      float f1 = (float)he[1];
      float f2 = (float)he[2];
      acc0 += f0 * (float)Td[0];      // lam'
      acc1 += f1 * (float)Td[128];    // a0'
      acc2 += f1 * (float)Td[256];    // a1'
      acc3 += f1 * (float)Td[384];    // a2'
      acc4 += f2 * (float)Td[512];    // s00'
    } else {
      float f2 = (float)he[2];
      acc0 += f2 * (float)Td[640];    // s01'
      acc1 += f2 * (float)Td[768];    // s02'
      acc2 += f2 * (float)Td[896];    // s11'
      acc3 += f2 * (float)Td[1024];   // s12'
      acc4 += f2 * (float)Td[1152];   // s22'
    }
  }
  __half* mn = &msg[(size_t)n*1280 + o];
  int pb = ph * 5;
  mn[(pb+0)*128] = __float2half(acc0);
  mn[(pb+1)*128] = __float2half(acc1);
  mn[(pb+2)*128] = __float2half(acc2);
  mn[(pb+3)*128] = __float2half(acc3);
  mn[(pb+4)*128] = __float2half(acc4);
}

// ---------------------------------------------------------------------------
// Bracket: B = M*Y + Y*M ; decompose ; /(tnorm(B)+1) -> D2
// D2 may alias T1 (in-place): no __restrict__ on those params.
// ---------------------------------------------------------------------------
__global__ __launch_bounds__(256) void k_bracket(
    const __half* __restrict__ msgp, const __half* T1, __half* D2)
{
  int idx = blockIdx.x*256 + threadIdx.x;
  int n = idx >> 7, o = idx & 127;
  const __half* Mc = &msgp[(size_t)n*1280 + o];
  const __half* Yc = &T1[(size_t)n*1280 + o];
  float Mm[9], Ym[9];
  {
    float lam=(float)Mc[0], a0=(float)Mc[128], a1=(float)Mc[256], a2=(float)Mc[384];
    float s00=(float)Mc[512], s01=(float)Mc[640], s02=(float)Mc[768];
    float s11=(float)Mc[896], s12=(float)Mc[1024], s22=(float)Mc[1152];
    Mm[0]=lam+s00; Mm[1]=a0+s01;  Mm[2]=a1+s02;
    Mm[3]=s01-a0;  Mm[4]=lam+s11; Mm[5]=a2+s12;
    Mm[6]=s02-a1;  Mm[7]=s12-a2;  Mm[8]=lam+s22;
  }
  {
    float lam=(float)Yc[0], a0=(float)Yc[128], a1=(float)Yc[256], a2=(float)Yc[384];
    float s00=(float)Yc[512], s01=(float)Yc[640], s02=(float)Yc[768];
    float s11=(float)Yc[896], s12=(float)Yc[1024], s22=(float)Yc[1152];
    Ym[0]=lam+s00; Ym[1]=a0+s01;  Ym[2]=a1+s02;
    Ym[3]=s01-a0;  Ym[4]=lam+s11; Ym[5]=a2+s12;
    Ym[6]=s02-a1;  Ym[7]=s12-a2;  Ym[8]=lam+s22;
  }
  float B[9];
  #pragma unroll
  for (int i = 0; i < 3; ++i) {
    #pragma unroll
    for (int j = 0; j < 3; ++j) {
      float s = 0.f;
      #pragma unroll
      for (int k = 0; k < 3; ++k)
        s += Mm[i*3+k]*Ym[k*3+j] + Ym[i*3+k]*Mm[k*3+j];
      B[i*3+j] = s;
    }
  }
  float lamb = (B[0]+B[4]+B[8]) * (1.f/3.f);
  float ss = 0.f;
  #pragma unroll
  for (int qq = 0; qq < 9; ++qq) ss += B[qq]*B[qq];
  float inv = 1.f / (fmaxf(ss, 0.01f) + 1.f);
  __half* Dn = &D2[(size_t)n*1280 + o];
  Dn[0]    = __float2half(lamb*inv);
  Dn[128]  = __float2half(0.5f*(B[1]-B[3])*inv);
  Dn[256]  = __float2half(0.5f*(B[2]-B[6])*inv);
  Dn[384]  = __float2half(0.5f*(B[5]-B[7])*inv);
  Dn[512]  = __float2half((B[0]-lamb)*inv);
  Dn[640]  = __float2half(0.5f*(B[1]+B[3])*inv);
  Dn[768]  = __float2half(0.5f*(B[2]+B[6])*inv);
  Dn[896]  = __float2half((B[4]-lamb)*inv);
  Dn[1024] = __float2half(0.5f*(B[5]+B[7])*inv);
  Dn[1152] = __float2half((B[8]-lamb)*inv);
}

// ---------------------------------------------------------------------------
// Final: out = Xn + reconstruct(Tb)
// ---------------------------------------------------------------------------
__global__ __launch_bounds__(256) void k_final(
    const __half* __restrict__ Xn, const __half* __restrict__ Tb,
    float* __restrict__ out)
{
  int idx = blockIdx.x*256 + threadIdx.x;
  int n = idx >> 7, o = idx & 127;
  const __half* Tc = &Tb[(size_t)n*1280 + o];
  float lam=(float)Tc[0], a0=(float)Tc[128], a1=(float)Tc[256], a2=(float)Tc[384];
  float s00=(float)Tc[512], s01=(float)Tc[640], s02=(float)Tc[768];
  float s11=(float)Tc[896], s12=(float)Tc[1024], s22=(float)Tc[1152];
  const __half* xc = &Xn[(size_t)n*1152 + o*9];
  float* oc = &out[(size_t)n*1152 + o*9];
  oc[0] = (float)xc[0] + lam + s00;
  oc[1] = (float)xc[1] + a0  + s01;
  oc[2] = (float)xc[2] + a1  + s02;
  oc[3] = (float)xc[3] - a0  + s01;
  oc[4] = (float)xc[4] + lam + s11;
  oc[5] = (float)xc[5] + a2  + s12;
  oc[6] = (float)xc[6] - a1  + s02;
  oc[7] = (float)xc[7] - a2  + s12;
  oc[8] = (float)xc[8] + lam + s22;
}

// ---------------------------------------------------------------------------
extern "C" void kernel_launch(void* const* d_in, const int* in_sizes, int n_in,
                              void* d_out, int out_size, void* d_ws, size_t ws_size,
                              hipStream_t stream)
{
  const float* X     = (const float*)d_in[0];
  const float* ew    = (const float*)d_in[1];
  const float* eattr = (const float*)d_in[2];
  const float* Wp    = (const float*)d_in[3];
  const float* bp    = (const float*)d_in[4];
  const float* Ws0   = (const float*)d_in[5];
  const float* bs0   = (const float*)d_in[6];
  const float* Ws1   = (const float*)d_in[7];
  const float* bs1   = (const float*)d_in[8];
  const float* Ws2   = (const float*)d_in[9];
  const float* bs2   = (const float*)d_in[10];
  const int*   eidx  = (const int*)d_in[11];
  const float* Wt0   = (const float*)d_in[12];
  const float* Wt1   = (const float*)d_in[13];
  const float* Wt2   = (const float*)d_in[14];
  const float* Wt3   = (const float*)d_in[15];
  const float* Wt4   = (const float*)d_in[16];
  const float* Wt5   = (const float*)d_in[17];
  float* out = (float*)d_out;

  // Packed lifetime-aliased layout, peak 254,161,920 B:
  //  A [0,          23,040,000)  Xn fp16                  [K1 -> final]
  //  B [23,040,000, 48,640,000)  T1 fp16 -> D2 (in-place) [K2 -> K4]
  //  C [48,640,000, 130,560,000) D1 -> h1 -> msg -> Tb    (81.92 MB)
  //  D [130,560,000,253,440,000) h0 -> ea                 (122.88 MB)
  //  csr [253,440,000, 254,161,920)
  const size_t NEED = 254161920;
  if (ws_size < NEED) return;   // diagnostic: poison-fail instead of fault

  char* base = (char*)d_ws;
  __half* Xn  = (__half*)(base);
  __half* T1  = (__half*)(base + 23040000);
  __half* D1  = (__half*)(base + 48640000);
  __half* h1  = (__half*)(base + 48640000);
  __half* msg = (__half*)(base + 48640000);
  __half* Tb  = (__half*)(base + 48640000);
  __half* h0  = (__half*)(base + 130560000);
  __half* ea  = (__half*)(base + 130560000);
  char*   csr = base + 253440000;
  int* off_  = (int*)csr;
  int* cur_  = (int*)(csr + 40960);
  int* elist = (int*)(csr + 81920);

  (void)in_sizes; (void)n_in; (void)out_size;

  // node prep + decompose
  k_node_prep<<<2500, 256, 0, stream>>>(X, Wp, bp, Xn, D1);

  // T' = clin(I,Wt0)/clin(A,Wt1)/clin(S,Wt2): 10 slices of [10000 x 128 x 128]
  k_gemm_mfma<_Float16, 128, false, false, true><<<dim3(2*79, 1, 10), 256, 0, stream>>>(
      (_Float16*)D1, 1280, Wt0, Wt1, Wt2, nullptr, nullptr, (_Float16*)T1, 1280, NN, 2);

  // edge MLP (cutoff folded into last layer's epilogue)
  k_gemm_mfma<float, 32, true, false, false><<<dim3(2*1250, 1, 1), 256, 0, stream>>>(
      eattr, 32, Ws0, nullptr, nullptr, bs0, nullptr, (_Float16*)h0, 128, EE, 2);
  k_gemm_mfma<_Float16, 128, true, false, false><<<dim3(4*1250, 1, 1), 256, 0, stream>>>(
      (_Float16*)h0, 128, Ws1, nullptr, nullptr, bs1, nullptr, (_Float16*)h1, 256, EE, 4);
  k_gemm_mfma<_Float16, 256, true, true, false><<<dim3(6*1250, 1, 1), 256, 0, stream>>>(
      (_Float16*)h1, 256, Ws2, nullptr, nullptr, bs2, ew, (_Float16*)ea, 384, EE, 6);

  // CSR over src
  k_zero_i<<<40, 256, 0, stream>>>(cur_, NN);
  k_hist<<<625, 256, 0, stream>>>(eidx, cur_);
  k_scan<<<1, 1024, 0, stream>>>(cur_, off_, cur_);
  k_scatter<<<625, 256, 0, stream>>>(eidx, cur_, elist);

  // message passing (gather T'[dst], reduce per src node)
  k_message<<<NN, 256, 0, stream>>>(ea, T1, eidx + EE, off_, elist, msg);

  // bracket + decompose + norm (D2 overwrites T1 in-place)
  k_bracket<<<5000, 256, 0, stream>>>(msg, T1, T1);

  // dX components = clin with Wt3/4/5
  k_gemm_mfma<_Float16, 128, false, false, true><<<dim3(2*79, 1, 10), 256, 0, stream>>>(
      (_Float16*)T1, 1280, Wt3, Wt4, Wt5, nullptr, nullptr, (_Float16*)Tb, 1280, NN, 2);

  // out = Xn + reconstruct(dX)
  k_final<<<5000, 256, 0, stream>>>(Xn, Tb, out);
}

// Round 4
// 450.710 us; speedup vs baseline: 2.7418x; 1.1601x over previous
//
#include <hip/hip_runtime.h>
#include <hip/hip_fp16.h>
#include <type_traits>

#define NN 10000
#define EE 160000

typedef _Float16 half8 __attribute__((ext_vector_type(8)));
typedef float    f32x4 __attribute__((ext_vector_type(4)));

// ---------------------------------------------------------------------------
// Node phase (split into 3 for MFMA):
//  pre : Xt[(n,ij)][c] fp16  <- X[n][c][ij] f32      (pack/transpose)
//  gemm: Xp[(n,ij)][o] = sum_c Xt * Wp[o][c] + bp[o] (k_gemm_mfma)
//  post: per (n,o): norm over 9 ij, decompose -> Xn[n][o][ij], D1[n][10][128]
// ---------------------------------------------------------------------------
__global__ __launch_bounds__(256) void k_node_pre(
    const float* __restrict__ X, _Float16* __restrict__ Xt)
{
  __shared__ float Xl[4*1152];
  const int n0 = blockIdx.x * 4;
  const int t = threadIdx.x;
  const float* src = X + (size_t)n0*1152;
  #pragma unroll
  for (int idx = t; idx < 4*1152; idx += 256) Xl[idx] = src[idx];
  __syncthreads();
  _Float16* dst = Xt + (size_t)n0*1152;
  #pragma unroll
  for (int idx = t; idx < 4*1152; idx += 256) {
    int node = idx / 1152, rem = idx - node*1152;
    int ij = rem >> 7, c = rem & 127;
    dst[idx] = (_Float16)Xl[node*1152 + c*9 + ij];   // stride-9 LDS: odd -> conflict-free
  }
}

__global__ __launch_bounds__(256) void k_node_post(
    const _Float16* __restrict__ Xp,
    __half* __restrict__ Xn, __half* __restrict__ D1)
{
  int idx = blockIdx.x*256 + threadIdx.x;
  int n = idx >> 7, o = idx & 127;
  float m[9], ss = 0.f;
  #pragma unroll
  for (int ij = 0; ij < 9; ++ij) {
    m[ij] = (float)Xp[((size_t)n*9 + ij)*128 + o];   // coalesced across o
    ss += m[ij]*m[ij];
  }
  ss = fmaxf(ss, 0.01f);
  float inv = 1.f / (ss + 1.f);
  #pragma unroll
  for (int ij = 0; ij < 9; ++ij) m[ij] *= inv;
  __half* xo = &Xn[(size_t)n*1152 + o*9];
  #pragma unroll
  for (int ij = 0; ij < 9; ++ij) xo[ij] = __float2half(m[ij]);
  float lam = (m[0]+m[4]+m[8]) * (1.f/3.f);
  __half* Dn = &D1[(size_t)n*1280];
  Dn[0*128+o] = __float2half(lam);
  Dn[1*128+o] = __float2half(0.5f*(m[1]-m[3]));
  Dn[2*128+o] = __float2half(0.5f*(m[2]-m[6]));
  Dn[3*128+o] = __float2half(0.5f*(m[5]-m[7]));
  Dn[4*128+o] = __float2half(m[0]-lam);
  Dn[5*128+o] = __float2half(0.5f*(m[1]+m[3]));
  Dn[6*128+o] = __float2half(0.5f*(m[2]+m[6]));
  Dn[7*128+o] = __float2half(m[4]-lam);
  Dn[8*128+o] = __float2half(0.5f*(m[5]+m[7]));
  Dn[9*128+o] = __float2half(m[8]-lam);
}

// ---------------------------------------------------------------------------
// MFMA GEMM: C[m][n] = post( sum_k A[m][k] * W[n][k] + bias[n] )
//   - mfma_f32_16x16x32_f16, fp32 accumulate
//   - 256 thr = 4 waves; BM=128 (wave w owns rows w*32..w*32+31), BN=64
//   - wave fragment-repeat acc[2][4] (2 row-frags x 4 col-frags of 16)
//   - A frags straight from global (16B/lane, aligned); W staged fp32->fp16
//     into LDS once per block, pitch KT+8 halves (conflict-free b128 reads)
//   - XCD-bijective swizzle (m204), n-tile fastest => A m-panel L2-resident
//   - PSEL: blockIdx.z = p in 0..9: W = p==0?W0 : p<4?W1 : W2; A,C col-offset p*128
// ---------------------------------------------------------------------------
template<typename TA, int KT, bool ACT, bool CUT, bool PSEL>
__global__ __launch_bounds__(256) void k_gemm_mfma(
    const TA* __restrict__ A, int lda,
    const float* __restrict__ W0, const float* __restrict__ W1, const float* __restrict__ W2,
    const float* __restrict__ bias, const float* __restrict__ cw,
    _Float16* __restrict__ C, int ldc,
    int M, int nTiles)
{
  constexpr int PITCH = KT + 8;
  __shared__ _Float16 Bs[64 * PITCH];
  const int t = threadIdx.x;

  // XCD-bijective block swizzle (m204): each XCD gets a contiguous chunk.
  int nwg = gridDim.x;
  int bid = blockIdx.x;
  int q = nwg >> 3, rr = nwg & 7;
  int xcd = bid & 7, ii = bid >> 3;
  int swz = (xcd < rr) ? xcd*(q+1) + ii : rr*(q+1) + (xcd-rr)*q + ii;
  int nt = swz % nTiles;
  int mt = swz / nTiles;

  const float* W = W0;
  int coff = 0;
  if (PSEL) {
    int p = blockIdx.z;
    W = (p == 0) ? W0 : (p < 4 ? W1 : W2);
    coff = p * 128;
  }
  const int n0 = nt * 64;
  const int m0 = mt * 128;

  // stage B strip [64][KT] fp32 -> fp16 LDS
  #pragma unroll 4
  for (int idx = t; idx < 64*KT; idx += 256) {
    int nn = idx / KT, kk = idx & (KT-1);
    Bs[nn*PITCH + kk] = (_Float16)W[(size_t)(n0 + nn)*KT + kk];
  }
  __syncthreads();

  const int wave = t >> 6, lane = t & 63;
  const int lr = lane & 15, lq = lane >> 4;
  const int rowBase = m0 + wave*32;
  const int kBase = lq*8;

  f32x4 acc[2][4] = {};
  #pragma unroll
  for (int k0 = 0; k0 < KT; k0 += 32) {
    half8 a[2];
    #pragma unroll
    for (int r = 0; r < 2; ++r) {
      int gm = rowBase + r*16 + lr;
      if (gm > M-1) gm = M-1;
      const TA* ap = A + (size_t)gm*lda + coff + k0 + kBase;
      if constexpr (std::is_same<TA, float>::value) {
        f32x4 u0 = *reinterpret_cast<const f32x4*>(ap);
        f32x4 u1 = *reinterpret_cast<const f32x4*>(ap + 4);
        half8 av;
        #pragma unroll
        for (int j = 0; j < 4; ++j) { av[j] = (_Float16)u0[j]; av[4+j] = (_Float16)u1[j]; }
        a[r] = av;
      } else {
        a[r] = *reinterpret_cast<const half8*>(ap);
      }
    }
    half8 b[4];
    #pragma unroll
    for (int c = 0; c < 4; ++c)
      b[c] = *reinterpret_cast<const half8*>(&Bs[(c*16 + lr)*PITCH + k0 + kBase]);
    #pragma unroll
    for (int r = 0; r < 2; ++r)
      #pragma unroll
      for (int c = 0; c < 4; ++c)
        acc[r][c] = __builtin_amdgcn_mfma_f32_16x16x32_f16(a[r], b[c], acc[r][c], 0, 0, 0);
  }

  // epilogue
  float bvv[4];
  #pragma unroll
  for (int c = 0; c < 4; ++c)
    bvv[c] = bias ? bias[n0 + c*16 + lr] : 0.f;
  #pragma unroll
  for (int r = 0; r < 2; ++r) {
    #pragma unroll
    for (int j = 0; j < 4; ++j) {
      int gm = rowBase + r*16 + lq*4 + j;   // C/D: col=lane&15, row=(lane>>4)*4+reg
      if (gm >= M) continue;
      float Cf = 1.f;
      if (CUT) {
        float wv = cw[gm];
        Cf = (wv < 5.f) ? 0.5f*(__cosf(wv*0.62831853071795864769f) + 1.f) : 0.f;
      }
      _Float16* crow = C + (size_t)gm*ldc + coff + n0;
      #pragma unroll
      for (int c = 0; c < 4; ++c) {
        float v = acc[r][c][j] + bvv[c];
        if (ACT) v = v / (1.f + __expf(-v));   // silu
        if (CUT) v *= Cf;
        crow[c*16 + lr] = (_Float16)v;
      }
    }
  }
}

// ---------------------------------------------------------------------------
// CSR build over src
// ---------------------------------------------------------------------------
__global__ void k_zero_i(int* __restrict__ p, int n) {
  int i = blockIdx.x*256 + threadIdx.x;
  if (i < n) p[i] = 0;
}
__global__ void k_hist(const int* __restrict__ src, int* __restrict__ cnt) {
  int e = blockIdx.x*256 + threadIdx.x;
  if (e < EE) atomicAdd(&cnt[src[e]], 1);
}
__global__ __launch_bounds__(1024) void k_scan(const int* __restrict__ cnt,
                                               int* __restrict__ off,
                                               int* __restrict__ cur) {
  __shared__ int s[1024];
  __shared__ int carry;
  int t = threadIdx.x;
  if (t == 0) carry = 0;
  __syncthreads();
  for (int base = 0; base < NN; base += 1024) {
    int i = base + t;
    int v = (i < NN) ? cnt[i] : 0;
    s[t] = v; __syncthreads();
    for (int d = 1; d < 1024; d <<= 1) {
      int x = (t >= d) ? s[t-d] : 0; __syncthreads();
      s[t] += x; __syncthreads();
    }
    int incl = s[t];
    int total = s[1023];
    int excl = incl - v + carry;
    if (i < NN) { off[i] = excl; cur[i] = excl; }
    __syncthreads();
    if (t == 0) carry += total;
    __syncthreads();
  }
  if (t == 0) off[NN] = carry;
}
__global__ void k_scatter(const int* __restrict__ src, int* __restrict__ cur,
                          int* __restrict__ elist) {
  int e = blockIdx.x*256 + threadIdx.x;
  if (e < EE) { int pos = atomicAdd(&cur[src[e]], 1); elist[pos] = e; }
}

// ---------------------------------------------------------------------------
// Message passing: one block per node; decomposed accumulation (I:1,A:3,S:6).
// ea already includes the cutoff factor.
// ---------------------------------------------------------------------------
__global__ __launch_bounds__(256) void k_message(
    const __half* __restrict__ ea, const __half* __restrict__ T1,
    const int* __restrict__ dstArr,
    const int* __restrict__ off, const int* __restrict__ elist,
    __half* __restrict__ msg)
{
  int n = blockIdx.x;
  int t = threadIdx.x;
  int o = t & 127, ph = t >> 7;
  int e0 = off[n], e1 = off[n+1];
  float acc0=0.f, acc1=0.f, acc2=0.f, acc3=0.f, acc4=0.f;
  for (int ii = e0; ii < e1; ++ii) {
    int e = elist[ii];
    int d = dstArr[e];
    const __half* he = &ea[(size_t)e*384 + 3*o];
    const __half* Td = &T1[(size_t)d*1280 + o];
    if (ph == 0) {
      float f0 = (float)he[0];
      float f1 = (float)he[1];
      float f2 = (float)he[2];
      acc0 += f0 * (float)Td[0];      // lam'
      acc1 += f1 * (float)Td[128];    // a0'
      acc2 += f1 * (float)Td[256];    // a1'
      acc3 += f1 * (float)Td[384];    // a2'
      acc4 += f2 * (float)Td[512];    // s00'
    } else {
      float f2 = (float)he[2];
      acc0 += f2 * (float)Td[640];    // s01'
      acc1 += f2 * (float)Td[768];    // s02'
      acc2 += f2 * (float)Td[896];    // s11'
      acc3 += f2 * (float)Td[1024];   // s12'
      acc4 += f2 * (float)Td[1152];   // s22'
    }
  }
  __half* mn = &msg[(size_t)n*1280 + o];
  int pb = ph * 5;
  mn[(pb+0)*128] = __float2half(acc0);
  mn[(pb+1)*128] = __float2half(acc1);
  mn[(pb+2)*128] = __float2half(acc2);
  mn[(pb+3)*128] = __float2half(acc3);
  mn[(pb+4)*128] = __float2half(acc4);
}

// ---------------------------------------------------------------------------
// Bracket: B = M*Y + Y*M ; decompose ; /(tnorm(B)+1) -> D2
// D2 may alias T1 (in-place): no __restrict__ on those params.
// ---------------------------------------------------------------------------
__global__ __launch_bounds__(256) void k_bracket(
    const __half* __restrict__ msgp, const __half* T1, __half* D2)
{
  int idx = blockIdx.x*256 + threadIdx.x;
  int n = idx >> 7, o = idx & 127;
  const __half* Mc = &msgp[(size_t)n*1280 + o];
  const __half* Yc = &T1[(size_t)n*1280 + o];
  float Mm[9], Ym[9];
  {
    float lam=(float)Mc[0], a0=(float)Mc[128], a1=(float)Mc[256], a2=(float)Mc[384];
    float s00=(float)Mc[512], s01=(float)Mc[640], s02=(float)Mc[768];
    float s11=(float)Mc[896], s12=(float)Mc[1024], s22=(float)Mc[1152];
    Mm[0]=lam+s00; Mm[1]=a0+s01;  Mm[2]=a1+s02;
    Mm[3]=s01-a0;  Mm[4]=lam+s11; Mm[5]=a2+s12;
    Mm[6]=s02-a1;  Mm[7]=s12-a2;  Mm[8]=lam+s22;
  }
  {
    float lam=(float)Yc[0], a0=(float)Yc[128], a1=(float)Yc[256], a2=(float)Yc[384];
    float s00=(float)Yc[512], s01=(float)Yc[640], s02=(float)Yc[768];
    float s11=(float)Yc[896], s12=(float)Yc[1024], s22=(float)Yc[1152];
    Ym[0]=lam+s00; Ym[1]=a0+s01;  Ym[2]=a1+s02;
    Ym[3]=s01-a0;  Ym[4]=lam+s11; Ym[5]=a2+s12;
    Ym[6]=s02-a1;  Ym[7]=s12-a2;  Ym[8]=lam+s22;
  }
  float B[9];
  #pragma unroll
  for (int i = 0; i < 3; ++i) {
    #pragma unroll
    for (int j = 0; j < 3; ++j) {
      float s = 0.f;
      #pragma unroll
      for (int k = 0; k < 3; ++k)
        s += Mm[i*3+k]*Ym[k*3+j] + Ym[i*3+k]*Mm[k*3+j];
      B[i*3+j] = s;
    }
  }
  float lamb = (B[0]+B[4]+B[8]) * (1.f/3.f);
  float ss = 0.f;
  #pragma unroll
  for (int qq = 0; qq < 9; ++qq) ss += B[qq]*B[qq];
  float inv = 1.f / (fmaxf(ss, 0.01f) + 1.f);
  __half* Dn = &D2[(size_t)n*1280 + o];
  Dn[0]    = __float2half(lamb*inv);
  Dn[128]  = __float2half(0.5f*(B[1]-B[3])*inv);
  Dn[256]  = __float2half(0.5f*(B[2]-B[6])*inv);
  Dn[384]  = __float2half(0.5f*(B[5]-B[7])*inv);
  Dn[512]  = __float2half((B[0]-lamb)*inv);
  Dn[640]  = __float2half(0.5f*(B[1]+B[3])*inv);
  Dn[768]  = __float2half(0.5f*(B[2]+B[6])*inv);
  Dn[896]  = __float2half((B[4]-lamb)*inv);
  Dn[1024] = __float2half(0.5f*(B[5]+B[7])*inv);
  Dn[1152] = __float2half((B[8]-lamb)*inv);
}

// ---------------------------------------------------------------------------
// Final: out = Xn + reconstruct(Tb)
// ---------------------------------------------------------------------------
__global__ __launch_bounds__(256) void k_final(
    const __half* __restrict__ Xn, const __half* __restrict__ Tb,
    float* __restrict__ out)
{
  int idx = blockIdx.x*256 + threadIdx.x;
  int n = idx >> 7, o = idx & 127;
  const __half* Tc = &Tb[(size_t)n*1280 + o];
  float lam=(float)Tc[0], a0=(float)Tc[128], a1=(float)Tc[256], a2=(float)Tc[384];
  float s00=(float)Tc[512], s01=(float)Tc[640], s02=(float)Tc[768];
  float s11=(float)Tc[896], s12=(float)Tc[1024], s22=(float)Tc[1152];
  const __half* xc = &Xn[(size_t)n*1152 + o*9];
  float* oc = &out[(size_t)n*1152 + o*9];
  oc[0] = (float)xc[0] + lam + s00;
  oc[1] = (float)xc[1] + a0  + s01;
  oc[2] = (float)xc[2] + a1  + s02;
  oc[3] = (float)xc[3] - a0  + s01;
  oc[4] = (float)xc[4] + lam + s11;
  oc[5] = (float)xc[5] + a2  + s12;
  oc[6] = (float)xc[6] - a1  + s02;
  oc[7] = (float)xc[7] - a2  + s12;
  oc[8] = (float)xc[8] + lam + s22;
}

// ---------------------------------------------------------------------------
extern "C" void kernel_launch(void* const* d_in, const int* in_sizes, int n_in,
                              void* d_out, int out_size, void* d_ws, size_t ws_size,
                              hipStream_t stream)
{
  const float* X     = (const float*)d_in[0];
  const float* ew    = (const float*)d_in[1];
  const float* eattr = (const float*)d_in[2];
  const float* Wp    = (const float*)d_in[3];
  const float* bp    = (const float*)d_in[4];
  const float* Ws0   = (const float*)d_in[5];
  const float* bs0   = (const float*)d_in[6];
  const float* Ws1   = (const float*)d_in[7];
  const float* bs1   = (const float*)d_in[8];
  const float* Ws2   = (const float*)d_in[9];
  const float* bs2   = (const float*)d_in[10];
  const int*   eidx  = (const int*)d_in[11];
  const float* Wt0   = (const float*)d_in[12];
  const float* Wt1   = (const float*)d_in[13];
  const float* Wt2   = (const float*)d_in[14];
  const float* Wt3   = (const float*)d_in[15];
  const float* Wt4   = (const float*)d_in[16];
  const float* Wt5   = (const float*)d_in[17];
  float* out = (float*)d_out;

  // Packed lifetime-aliased layout, peak 254,161,920 B:
  //  A [0,          23,040,000)  Xn fp16                  [node_post -> final]
  //  B [23,040,000, 48,640,000)  T1 fp16 -> D2 (in-place) [K2 -> K4]
  //  C [48,640,000, 130,560,000) {D1 | Xt | Xp} -> h1 -> msg -> Tb
  //  D [130,560,000,253,440,000) h0 -> ea                 (122.88 MB)
  //  csr [253,440,000, 254,161,920)
  const size_t NEED = 254161920;
  if (ws_size < NEED) return;   // diagnostic: poison-fail instead of fault

  char* base = (char*)d_ws;
  __half*   Xn  = (__half*)(base);
  __half*   T1  = (__half*)(base + 23040000);
  __half*   D1  = (__half*)(base + 48640000);          // 25.6 MB [node_post -> K2]
  _Float16* Xt  = (_Float16*)(base + 74240000);        // 23.04 MB [pre -> gemm]
  _Float16* Xp  = (_Float16*)(base + 97280000);        // 23.04 MB [gemm -> post]
  __half*   h1  = (__half*)(base + 48640000);
  __half*   msg = (__half*)(base + 48640000);
  __half*   Tb  = (__half*)(base + 48640000);
  __half*   h0  = (__half*)(base + 130560000);
  __half*   ea  = (__half*)(base + 130560000);
  char*     csr = base + 253440000;
  int* off_  = (int*)csr;
  int* cur_  = (int*)(csr + 40960);
  int* elist = (int*)(csr + 81920);

  (void)in_sizes; (void)n_in; (void)out_size;

  // node phase: pack -> MFMA GEMM (M=90000,K=128,N=128, bias=bp) -> norm/decompose
  k_node_pre<<<2500, 256, 0, stream>>>(X, Xt);
  k_gemm_mfma<_Float16, 128, false, false, false><<<dim3(2*704, 1, 1), 256, 0, stream>>>(
      Xt, 128, Wp, nullptr, nullptr, bp, nullptr, Xp, 128, 9*NN, 2);
  k_node_post<<<5000, 256, 0, stream>>>(Xp, Xn, D1);

  // T' = clin(I,Wt0)/clin(A,Wt1)/clin(S,Wt2): 10 slices of [10000 x 128 x 128]
  k_gemm_mfma<_Float16, 128, false, false, true><<<dim3(2*79, 1, 10), 256, 0, stream>>>(
      (_Float16*)D1, 1280, Wt0, Wt1, Wt2, nullptr, nullptr, (_Float16*)T1, 1280, NN, 2);

  // edge MLP (cutoff folded into last layer's epilogue)
  k_gemm_mfma<float, 32, true, false, false><<<dim3(2*1250, 1, 1), 256, 0, stream>>>(
      eattr, 32, Ws0, nullptr, nullptr, bs0, nullptr, (_Float16*)h0, 128, EE, 2);
  k_gemm_mfma<_Float16, 128, true, false, false><<<dim3(4*1250, 1, 1), 256, 0, stream>>>(
      (_Float16*)h0, 128, Ws1, nullptr, nullptr, bs1, nullptr, (_Float16*)h1, 256, EE, 4);
  k_gemm_mfma<_Float16, 256, true, true, false><<<dim3(6*1250, 1, 1), 256, 0, stream>>>(
      (_Float16*)h1, 256, Ws2, nullptr, nullptr, bs2, ew, (_Float16*)ea, 384, EE, 6);

  // CSR over src
  k_zero_i<<<40, 256, 0, stream>>>(cur_, NN);
  k_hist<<<625, 256, 0, stream>>>(eidx, cur_);
  k_scan<<<1, 1024, 0, stream>>>(cur_, off_, cur_);
  k_scatter<<<625, 256, 0, stream>>>(eidx, cur_, elist);

  // message passing (gather T'[dst], reduce per src node)
  k_message<<<NN, 256, 0, stream>>>(ea, T1, eidx + EE, off_, elist, msg);

  // bracket + decompose + norm (D2 overwrites T1 in-place)
  k_bracket<<<5000, 256, 0, stream>>>(msg, T1, T1);

  // dX components = clin with Wt3/4/5
  k_gemm_mfma<_Float16, 128, false, false, true><<<dim3(2*79, 1, 10), 256, 0, stream>>>(
      (_Float16*)T1, 1280, Wt3, Wt4, Wt5, nullptr, nullptr, (_Float16*)Tb, 1280, NN, 2);

  // out = Xn + reconstruct(dX)
  k_final<<<5000, 256, 0, stream>>>(Xn, Tb, out);
}